// Round 8
// baseline (358.153 us; speedup 1.0000x reference)
//
#include <hip/hip_runtime.h>
#include <hip/hip_bf16.h>
#include <math.h>

#define D_DIM 1024
#define L_DIM 4096
#define B_DIM 2
#define K_DIM 256           // D/4
#define N6    1536          // K*6
#define M_ROWS 8192         // B*L
#define CHUNKS 256
#define CHUNK_LEN 16
#define HALF_PI 1.57079632679489662f

typedef __attribute__((ext_vector_type(8))) short short8;
typedef __attribute__((ext_vector_type(4))) float f32x4;
typedef unsigned short us;

__device__ __forceinline__ float bf2f(us u) {
    union { unsigned int i; float f; } c; c.i = ((unsigned int)u) << 16; return c.f;
}
__device__ __forceinline__ us f2bf(float v) {
    __hip_bfloat16 h = __float2bfloat16(v);
    return *(us*)&h;
}
__device__ __forceinline__ float tanh_fast(float x) {
    return 1.0f - 2.0f / (1.0f + __expf(2.0f * x));
}
// tanh-approx gelu (max dev from exact erf-gelu ~3e-3; threshold has 4x headroom)
__device__ __forceinline__ float gelu_fast(float x) {
    return x / (1.0f + __expf(-1.5957691216057308f * x * (1.0f + 0.044715f * x * x)));
}

// ---------------- rotor helpers ----------------
__device__ __forceinline__ void rotor_from_angles(const float a[6], float& s, float b[6]) {
    float m2 = a[0]*a[0] + a[1]*a[1] + a[2]*a[2] + a[3]*a[3] + a[4]*a[4] + a[5]*a[5];
    float mag = fmaxf(sqrtf(m2), 1e-8f);
    s = __cosf(mag);                 // mag <= pi/2*sqrt(6) ~ 3.85, in fast range
    float f = __sinf(mag) / mag;
    #pragma unroll
    for (int i = 0; i < 6; ++i) b[i] = f * a[i];
}
__device__ __forceinline__ void apply_rotor(float s, const float b[6], const float v[4], float o[4]) {
    float t12 = b[0], t13 = b[1], t14 = b[2], t23 = b[3], t24 = b[4], t34 = b[5];
    float v1 = v[0], v2 = v[1], v3 = v[2], v4 = v[3];
    float s2 = s * s;
    float ts = 2.0f * s;
    o[0] = v1 * (s2 - t12*t12 - t13*t13 - t14*t14) + ts * ( v2*t12 + v3*t13 + v4*t14);
    o[1] = v2 * (s2 - t12*t12 - t23*t23 - t24*t24) + ts * (-v1*t12 + v3*t23 + v4*t24);
    o[2] = v3 * (s2 - t13*t13 - t23*t23 - t34*t34) + ts * (-v1*t13 - v2*t23 + v4*t34);
    o[3] = v4 * (s2 - t14*t14 - t24*t24 - t34*t34) + ts * (-v1*t14 - v2*t24 - v3*t34);
}

// ---------------- weight pack: W[K][N] fp32 -> Bpack[nfrag][ktile][lane*8] bf16 -------
// frag (nf, kt): lane l element j = W[kt*32 + (l>>4)*8 + j][nf*16 + (l&15)]
__global__ __launch_bounds__(256)
void pack_b4(const float* __restrict__ w0, const float* __restrict__ w1,
             const float* __restrict__ w2, const float* __restrict__ w3,
             us* __restrict__ o0, us* __restrict__ o1,
             us* __restrict__ o2, us* __restrict__ o3, int Kd, int N)
{
    const float* W = (blockIdx.z == 0) ? w0 : (blockIdx.z == 1) ? w1 : (blockIdx.z == 2) ? w2 : w3;
    us* O = (blockIdx.z == 0) ? o0 : (blockIdx.z == 1) ? o1 : (blockIdx.z == 2) ? o2 : o3;
    if (W == nullptr) return;
    int nf = blockIdx.x;                         // N/16 frag-rows
    int kt = blockIdx.y * 4 + (threadIdx.x >> 6);
    int l = threadIdx.x & 63;
    int n = nf * 16 + (l & 15);
    int k0 = kt * 32 + (l >> 4) * 8;
    union { us u[8]; uint4 v; } pk;
    #pragma unroll
    for (int j = 0; j < 8; ++j)
        pk.u[j] = f2bf(W[(size_t)(k0 + j) * N + n]);
    *(uint4*)(O + ((size_t)nf * (Kd >> 5) + kt) * 512 + l * 8) = pk.v;
}

// ---------------- fp32 -> bf16 convert ----------------
__global__ __launch_bounds__(256)
void cvt_bf16_kernel(const float* __restrict__ in, us* __restrict__ out)
{
    size_t i = ((size_t)blockIdx.x * 256 + threadIdx.x) * 8;
    float4 v0 = *(const float4*)(in + i);
    float4 v1 = *(const float4*)(in + i + 4);
    union { us u[8]; uint4 v; } pk;
    pk.u[0] = f2bf(v0.x); pk.u[1] = f2bf(v0.y); pk.u[2] = f2bf(v0.z); pk.u[3] = f2bf(v0.w);
    pk.u[4] = f2bf(v1.x); pk.u[5] = f2bf(v1.y); pk.u[6] = f2bf(v1.z); pk.u[7] = f2bf(v1.w);
    *(uint4*)(out + i) = pk.v;
}

// ---------------- XCD-chunked block swizzle (bijective, nwg % 8 == 0) ----------------
__device__ __forceinline__ int xcd_swz(int bid, int nwg) {
    int cpx = nwg >> 3;
    return (bid & 7) * cpx + (bid >> 3);
}

// ============ 128x128 GEMM core: NO LDS, all-register, 2-deep pipelined ============
// 4 waves, wave tile 64x64, frags 4x4, 16 MFMA / K-tile / wave.
// A-frags read directly from row-major global (16B/lane, 4-lane groups = 64B lines,
// L1/L2-resident panels). B pre-packed fragment-order (lane*8, perfectly coalesced).
// No barriers: latency hidden by TLP (12 waves/CU) + 1-tile register double-buffer.

__device__ __forceinline__ void gemm128_core(
    const us* __restrict__ Ab, const us* __restrict__ Bp, int Kd, int bn,
    f32x4 (&acc)[4][4])
{
    const int tid = threadIdx.x;
    const int l = tid & 63, w = tid >> 6;
    const int wr = w >> 1, wc = w & 1;
    const int fr = l & 15, fq = l >> 4;
    const int nkt = Kd >> 5;

    #pragma unroll
    for (int i = 0; i < 4; ++i)
        #pragma unroll
        for (int j = 0; j < 4; ++j)
            acc[i][j] = (f32x4){0.f, 0.f, 0.f, 0.f};

    // A fragment pointers: lane reads A[wr*64 + mi*16 + fr][t*32 + fq*8 .. +7]
    const us* aptr[4];
    #pragma unroll
    for (int mi = 0; mi < 4; ++mi)
        aptr[mi] = Ab + (size_t)(wr * 64 + mi * 16 + fr) * Kd + fq * 8;
    // B fragment pointers: nfrag = bn/16 + wc*4 + ni ; per-tile stride 512 shorts
    const us* bptr[4];
    #pragma unroll
    for (int ni = 0; ni < 4; ++ni)
        bptr[ni] = Bp + ((size_t)((bn >> 4) + wc * 4 + ni) * nkt) * 512 + l * 8;

    short8 a0[4], b0[4], a1[4], b1[4];
    #pragma unroll
    for (int i = 0; i < 4; ++i) {
        a0[i] = *(const short8*)(aptr[i]);
        b0[i] = *(const short8*)(bptr[i]);
    }

    for (int t = 0; t < nkt; t += 2) {
        // prefetch tile t+1 (nkt even => t+1 < nkt always)
        #pragma unroll
        for (int i = 0; i < 4; ++i) {
            a1[i] = *(const short8*)(aptr[i] + (t + 1) * 32);
            b1[i] = *(const short8*)(bptr[i] + (size_t)(t + 1) * 512);
        }
        __builtin_amdgcn_s_setprio(1);
        #pragma unroll
        for (int mi = 0; mi < 4; ++mi)
            #pragma unroll
            for (int ni = 0; ni < 4; ++ni)
                acc[mi][ni] = __builtin_amdgcn_mfma_f32_16x16x32_bf16(b0[ni], a0[mi], acc[mi][ni], 0, 0, 0);
        __builtin_amdgcn_s_setprio(0);
        // prefetch tile t+2 (clamped; redundant re-read on last iter, harmless)
        const int t2 = (t + 2 < nkt) ? (t + 2) : (nkt - 1);
        #pragma unroll
        for (int i = 0; i < 4; ++i) {
            a0[i] = *(const short8*)(aptr[i] + t2 * 32);
            b0[i] = *(const short8*)(bptr[i] + (size_t)t2 * 512);
        }
        __builtin_amdgcn_s_setprio(1);
        #pragma unroll
        for (int mi = 0; mi < 4; ++mi)
            #pragma unroll
            for (int ni = 0; ni < 4; ++ni)
                acc[mi][ni] = __builtin_amdgcn_mfma_f32_16x16x32_bf16(b1[ni], a1[mi], acc[mi][ni], 0, 0, 0);
        __builtin_amdgcn_s_setprio(0);
    }
    // output mapping: row = bm + wr*64 + mi*16 + fr; col = bn + wc*64 + ni*16 + fq*4 + v
}

// ---------------- GEMM A: x @ [wk1|wq1|wv], fused epilogues, bf16 out ----------------
__global__ __launch_bounds__(256, 3)
void gemm_fused3(const us* __restrict__ xb,
                 const us* __restrict__ w0p, const us* __restrict__ w1p, const us* __restrict__ w2p,
                 const float* __restrict__ b0, const float* __restrict__ b1, const float* __restrict__ b2,
                 us* __restrict__ o0, us* __restrict__ o1, us* __restrict__ o2)
{
    const int wg = xcd_swz(blockIdx.x, 1536);
    const int bm = (wg / 24) * 128;              // bm-major: 24 col-blocks share A-panel
    const int col = wg % 24;
    const int r = col >> 3;                      // 0=k,1=q,2=v
    const int bn = (col & 7) * 128;
    const us* Bp = (r == 0) ? w0p : (r == 1) ? w1p : w2p;
    const float* bias = (r == 0) ? b0 : (r == 1) ? b1 : b2;
    us* outp = (r == 0) ? o0 : (r == 1) ? o1 : o2;
    f32x4 acc[4][4];
    gemm128_core(xb + (size_t)bm * D_DIM, Bp, D_DIM, bn, acc);
    const int l = threadIdx.x & 63, w = threadIdx.x >> 6;
    const int wr = w >> 1, wc = w & 1, fr = l & 15, fq = l >> 4;
    #pragma unroll
    for (int mi = 0; mi < 4; ++mi) {
        int row = bm + wr * 64 + mi * 16 + fr;
        #pragma unroll
        for (int ni = 0; ni < 4; ++ni) {
            int c0 = bn + wc * 64 + ni * 16 + fq * 4;
            float4 bs = *(const float4*)(bias + c0);
            float v0 = acc[mi][ni][0] + bs.x, v1 = acc[mi][ni][1] + bs.y;
            float v2 = acc[mi][ni][2] + bs.z, v3 = acc[mi][ni][3] + bs.w;
            if (r < 2) { v0 = gelu_fast(v0); v1 = gelu_fast(v1); v2 = gelu_fast(v2); v3 = gelu_fast(v3); }
            ushort4 pk; pk.x = f2bf(v0); pk.y = f2bf(v1); pk.z = f2bf(v2); pk.w = f2bf(v3);
            *(ushort4*)(outp + (size_t)row * D_DIM + c0) = pk;
        }
    }
}

// ---------------- GEMM B: angles = tanh(H @ w2 + b2)*pi/2, bf16 out ----------------
__global__ __launch_bounds__(256, 3)
void gemm_angles(const us* __restrict__ Hk, const us* __restrict__ Hq,
                 const us* __restrict__ wk2p, const us* __restrict__ wq2p,
                 const float* __restrict__ bk2, const float* __restrict__ bq2,
                 us* __restrict__ ak, us* __restrict__ aq)
{
    const int wg = xcd_swz(blockIdx.x, 1536);
    const int z = wg / 768;
    const int rem = wg % 768;
    const int bm = (rem / 12) * 128;             // bm-major within z
    const int bn = (rem % 12) * 128;
    const us* A  = z ? Hq : Hk;
    const us* Bp = z ? wq2p : wk2p;
    const float* bias = z ? bq2 : bk2;
    us* outp = z ? aq : ak;
    f32x4 acc[4][4];
    gemm128_core(A + (size_t)bm * D_DIM, Bp, D_DIM, bn, acc);
    const int l = threadIdx.x & 63, w = threadIdx.x >> 6;
    const int wr = w >> 1, wc = w & 1, fr = l & 15, fq = l >> 4;
    #pragma unroll
    for (int mi = 0; mi < 4; ++mi) {
        int row = bm + wr * 64 + mi * 16 + fr;
        #pragma unroll
        for (int ni = 0; ni < 4; ++ni) {
            int c0 = bn + wc * 64 + ni * 16 + fq * 4;
            float4 bs = *(const float4*)(bias + c0);
            ushort4 pk;
            pk.x = f2bf(tanh_fast(acc[mi][ni][0] + bs.x) * HALF_PI);
            pk.y = f2bf(tanh_fast(acc[mi][ni][1] + bs.y) * HALF_PI);
            pk.z = f2bf(tanh_fast(acc[mi][ni][2] + bs.z) * HALF_PI);
            pk.w = f2bf(tanh_fast(acc[mi][ni][3] + bs.w) * HALF_PI);
            *(ushort4*)(outp + (size_t)row * N6 + c0) = pk;
        }
    }
}

// ---------------- GEMM C: out = x + rn @ wo + bo, fp32 out ----------------
__global__ __launch_bounds__(256, 3)
void gemm_final(const us* __restrict__ rn, const us* __restrict__ wop,
                const float* __restrict__ bo, const float* __restrict__ x,
                float* __restrict__ out)
{
    const int wg = xcd_swz(blockIdx.x, 512);
    const int bm = (wg / 8) * 128;
    const int bn = (wg % 8) * 128;
    f32x4 acc[4][4];
    gemm128_core(rn + (size_t)bm * D_DIM, wop, D_DIM, bn, acc);
    const int l = threadIdx.x & 63, w = threadIdx.x >> 6;
    const int wr = w >> 1, wc = w & 1, fr = l & 15, fq = l >> 4;
    #pragma unroll
    for (int mi = 0; mi < 4; ++mi) {
        int row = bm + wr * 64 + mi * 16 + fr;
        #pragma unroll
        for (int ni = 0; ni < 4; ++ni) {
            int c0 = bn + wc * 64 + ni * 16 + fq * 4;
            size_t off = (size_t)row * D_DIM + c0;
            float4 bs = *(const float4*)(bo + c0);
            float4 rx = *(const float4*)(x + off);
            float4 o;
            o.x = acc[mi][ni][0] + bs.x + rx.x;
            o.y = acc[mi][ni][1] + bs.y + rx.y;
            o.z = acc[mi][ni][2] + bs.z + rx.z;
            o.w = acc[mi][ni][3] + bs.w + rx.w;
            *(float4*)(out + off) = o;
        }
    }
}

// ---------------- scan phase 1: rotate(value by key rotor) + per-chunk sums ----------------
__global__ __launch_bounds__(256)
void rot_chunk_sum(const us* __restrict__ value, const us* __restrict__ ak,
                   float4* __restrict__ sums)
{
    int bc = blockIdx.x;
    int b = bc >> 8, c = bc & 255;
    int k = threadIdx.x;
    float4 acc = make_float4(0.f, 0.f, 0.f, 0.f);
    size_t row0 = (size_t)b * L_DIM + c * CHUNK_LEN;
    for (int i = 0; i < CHUNK_LEN; ++i) {
        size_t row = row0 + i;
        ushort4 uv = *(const ushort4*)(value + row * D_DIM + k * 4);
        const unsigned int* ap = (const unsigned int*)(ak + row * N6 + k * 6);
        unsigned int a0 = ap[0], a1 = ap[1], a2 = ap[2];
        float a[6] = { bf2f(a0 & 0xffff), bf2f(a0 >> 16), bf2f(a1 & 0xffff),
                       bf2f(a1 >> 16), bf2f(a2 & 0xffff), bf2f(a2 >> 16) };
        float s, bb[6];
        rotor_from_angles(a, s, bb);
        float v[4] = {bf2f(uv.x), bf2f(uv.y), bf2f(uv.z), bf2f(uv.w)}, o[4];
        apply_rotor(s, bb, v, o);
        acc.x += o[0]; acc.y += o[1]; acc.z += o[2]; acc.w += o[3];
    }
    sums[(size_t)bc * 256 + k] = acc;
}

// ---------------- scan phase 2: exclusive scan of chunk sums ----------------
__global__ __launch_bounds__(256)
void scan_chunks_kernel(const float4* __restrict__ sums, float4* __restrict__ carry)
{
    int b = blockIdx.x >> 8;
    int k = blockIdx.x & 255;
    int c = threadIdx.x;
    __shared__ float4 sh[CHUNKS];
    float4 v = sums[((size_t)(b * CHUNKS + c)) * 256 + k];
    sh[c] = v;
    __syncthreads();
    for (int off = 1; off < CHUNKS; off <<= 1) {
        float4 t = make_float4(0.f, 0.f, 0.f, 0.f);
        if (c >= off) t = sh[c - off];
        __syncthreads();
        v.x += t.x; v.y += t.y; v.z += t.z; v.w += t.w;
        sh[c] = v;
        __syncthreads();
    }
    float4 ex = make_float4(0.f, 0.f, 0.f, 0.f);
    if (c > 0) ex = sh[c - 1];
    carry[((size_t)(b * CHUNKS + c)) * 256 + k] = ex;
}

// ---------------- scan phase 3: rotate+cumsum + reversed query rotor + 1/sqrt + LayerNorm ----------------
__global__ __launch_bounds__(256)
void scan_apply_ln(const us* __restrict__ value, const us* __restrict__ ak,
                   const us* __restrict__ aq, const float4* __restrict__ carry,
                   const float* __restrict__ g, const float* __restrict__ bta,
                   us* __restrict__ rn)
{
    int bc = blockIdx.x;
    int b = bc >> 8, c = bc & 255;
    int k = threadIdx.x;
    int wv = k >> 6, lane = k & 63;
    float4 run = carry[(size_t)bc * 256 + k];
    float4 gv = *(const float4*)(g + k * 4);
    float4 bv = *(const float4*)(bta + k * 4);
    __shared__ float reds[4], redq[4];
    for (int i = 0; i < CHUNK_LEN; ++i) {
        int l = c * CHUNK_LEN + i;
        size_t row = (size_t)b * L_DIM + l;
        ushort4 uv = *(const ushort4*)(value + row * D_DIM + k * 4);
        const unsigned int* akp = (const unsigned int*)(ak + row * N6 + k * 6);
        unsigned int ka0 = akp[0], ka1 = akp[1], ka2 = akp[2];
        float a[6] = { bf2f(ka0 & 0xffff), bf2f(ka0 >> 16), bf2f(ka1 & 0xffff),
                       bf2f(ka1 >> 16), bf2f(ka2 & 0xffff), bf2f(ka2 >> 16) };
        float s, bb[6];
        rotor_from_angles(a, s, bb);
        float v[4] = {bf2f(uv.x), bf2f(uv.y), bf2f(uv.z), bf2f(uv.w)}, o[4];
        apply_rotor(s, bb, v, o);
        run.x += o[0]; run.y += o[1]; run.z += o[2]; run.w += o[3];
        const unsigned int* aqp = (const unsigned int*)(aq + row * N6 + k * 6);
        unsigned int qa0 = aqp[0], qa1 = aqp[1], qa2 = aqp[2];
        float aq6[6] = { bf2f(qa0 & 0xffff), bf2f(qa0 >> 16), bf2f(qa1 & 0xffff),
                         bf2f(qa1 >> 16), bf2f(qa2 & 0xffff), bf2f(qa2 >> 16) };
        float qs, qb[6];
        rotor_from_angles(aq6, qs, qb);
        #pragma unroll
        for (int t = 0; t < 6; ++t) qb[t] = -qb[t];
        float mem[4] = {run.x, run.y, run.z, run.w}, o2[4];
        apply_rotor(qs, qb, mem, o2);
        float inv = rsqrtf((float)(l + 1));
        o2[0] *= inv; o2[1] *= inv; o2[2] *= inv; o2[3] *= inv;
        float sm = o2[0] + o2[1] + o2[2] + o2[3];
        float qm = o2[0]*o2[0] + o2[1]*o2[1] + o2[2]*o2[2] + o2[3]*o2[3];
        #pragma unroll
        for (int off = 1; off < 64; off <<= 1) {
            sm += __shfl_xor(sm, off);
            qm += __shfl_xor(qm, off);
        }
        if (lane == 0) { reds[wv] = sm; redq[wv] = qm; }
        __syncthreads();
        sm = reds[0] + reds[1] + reds[2] + reds[3];
        qm = redq[0] + redq[1] + redq[2] + redq[3];
        float mu = sm * (1.0f / 1024.0f);
        float var = qm * (1.0f / 1024.0f) - mu * mu;
        float rstd = rsqrtf(var + 1e-5f);
        ushort4 pk;
        pk.x = f2bf((o2[0] - mu) * rstd * gv.x + bv.x);
        pk.y = f2bf((o2[1] - mu) * rstd * gv.y + bv.y);
        pk.z = f2bf((o2[2] - mu) * rstd * gv.z + bv.z);
        pk.w = f2bf((o2[3] - mu) * rstd * gv.w + bv.w);
        *(ushort4*)(rn + row * D_DIM + k * 4) = pk;
        __syncthreads();
    }
}

extern "C" void kernel_launch(void* const* d_in, const int* in_sizes, int n_in,
                              void* d_out, int out_size, void* d_ws, size_t ws_size,
                              hipStream_t stream)
{
    const float* x   = (const float*)d_in[0];
    const float* wk1 = (const float*)d_in[1];
    const float* bk1 = (const float*)d_in[2];
    const float* wk2 = (const float*)d_in[3];
    const float* bk2 = (const float*)d_in[4];
    const float* wq1 = (const float*)d_in[5];
    const float* bq1 = (const float*)d_in[6];
    const float* wq2 = (const float*)d_in[7];
    const float* bq2 = (const float*)d_in[8];
    const float* wv  = (const float*)d_in[9];
    const float* bv  = (const float*)d_in[10];
    const float* lng = (const float*)d_in[11];
    const float* lnb = (const float*)d_in[12];
    const float* wo  = (const float*)d_in[13];
    const float* bo  = (const float*)d_in[14];
    float* out = (float*)d_out;

    char* ws = (char*)d_ws;
    us* xb    = (us*)(ws);                       // 16 MB (later aliased as rn)
    us* Hk    = (us*)(ws + (16ull  << 20));      // 16 MB
    us* Hq    = (us*)(ws + (32ull  << 20));      // 16 MB
    us* val   = (us*)(ws + (48ull  << 20));      // 16 MB
    us* ak    = (us*)(ws + (64ull  << 20));      // 24 MB
    us* aq    = (us*)(ws + (88ull  << 20));      // 24 MB
    float4* sums  = (float4*)(ws + (112ull << 20)); // 2 MB
    float4* carry = (float4*)(ws + (114ull << 20)); // 2 MB
    us* wk1p  = (us*)(ws + (116ull << 20));      // 2 MB
    us* wq1p  = (us*)(ws + (118ull << 20));      // 2 MB
    us* wvp   = (us*)(ws + (120ull << 20));      // 2 MB
    us* wop   = (us*)(ws + (122ull << 20));      // 2 MB
    us* wk2p  = (us*)(ws + (124ull << 20));      // 3 MB
    us* wq2p  = (us*)(ws + (127ull << 20));      // 3 MB -> 130 MB total
    us* rn    = xb;                              // alias: xb dead after gemm_fused3

    dim3 blk(256);
    // weight packs: 4x DxD, 2x DxN6  (grid: N/16 frags x K/128 x z)
    pack_b4<<<dim3(D_DIM / 16, D_DIM / 128, 4), blk, 0, stream>>>(
        wk1, wq1, wv, wo, wk1p, wq1p, wvp, wop, D_DIM, D_DIM);
    pack_b4<<<dim3(N6 / 16, D_DIM / 128, 2), blk, 0, stream>>>(
        wk2, wq2, nullptr, nullptr, wk2p, wq2p, nullptr, nullptr, D_DIM, N6);
    cvt_bf16_kernel<<<dim3(M_ROWS * D_DIM / (256 * 8)), blk, 0, stream>>>(x, xb);

    // GEMM A: x @ [wk1|wq1|wv] -> Hk, Hq, val (bf16); 1536 blocks, bm-major + XCD chunk
    gemm_fused3<<<dim3(1536), blk, 0, stream>>>(
        xb, wk1p, wq1p, wvp, bk1, bq1, bv, Hk, Hq, val);
    // GEMM B: angles (k then q); 1536 blocks
    gemm_angles<<<dim3(1536), blk, 0, stream>>>(
        Hk, Hq, wk2p, wq2p, bk2, bq2, ak, aq);
    // scan chain
    rot_chunk_sum<<<dim3(B_DIM * CHUNKS), blk, 0, stream>>>(val, ak, sums);
    scan_chunks_kernel<<<dim3(B_DIM * K_DIM), blk, 0, stream>>>(sums, carry);
    scan_apply_ln<<<dim3(B_DIM * CHUNKS), blk, 0, stream>>>(val, ak, aq, carry, lng, lnb, rn);
    // GEMM C: out = x + rn @ wo + bo; 512 blocks
    gemm_final<<<dim3(512), blk, 0, stream>>>(rn, wop, bo, x, out);
}

// Round 9
// 229.295 us; speedup vs baseline: 1.5620x; 1.5620x over previous
//
#include <hip/hip_runtime.h>
#include <hip/hip_bf16.h>
#include <math.h>

#define D_DIM 1024
#define L_DIM 4096
#define B_DIM 2
#define K_DIM 256           // D/4
#define N6    1536          // K*6
#define M_ROWS 8192         // B*L
#define CHUNKS 256
#define CHUNK_LEN 16
#define HALF_PI 1.57079632679489662f

typedef __attribute__((ext_vector_type(8))) short short8;
typedef __attribute__((ext_vector_type(4))) float f32x4;
typedef unsigned short us;

__device__ __forceinline__ void gload_lds16(const void* g, void* l) {
    __builtin_amdgcn_global_load_lds(
        (const __attribute__((address_space(1))) unsigned int*)g,
        (__attribute__((address_space(3))) unsigned int*)l,
        16, 0, 0);
}
__device__ __forceinline__ float bf2f(us u) {
    union { unsigned int i; float f; } c; c.i = ((unsigned int)u) << 16; return c.f;
}
__device__ __forceinline__ us f2bf(float v) {
    __hip_bfloat16 h = __float2bfloat16(v);
    return *(us*)&h;
}
__device__ __forceinline__ float tanh_fast(float x) {
    return 1.0f - 2.0f / (1.0f + __expf(2.0f * x));
}
// tanh-approx gelu (max dev from exact erf-gelu ~3e-3; threshold has 4x headroom)
__device__ __forceinline__ float gelu_fast(float x) {
    return x / (1.0f + __expf(-1.5957691216057308f * x * (1.0f + 0.044715f * x * x)));
}

// ---------------- rotor helpers ----------------
__device__ __forceinline__ void rotor_from_angles(const float a[6], float& s, float b[6]) {
    float m2 = a[0]*a[0] + a[1]*a[1] + a[2]*a[2] + a[3]*a[3] + a[4]*a[4] + a[5]*a[5];
    float mag = fmaxf(sqrtf(m2), 1e-8f);
    s = __cosf(mag);                 // mag <= pi/2*sqrt(6) ~ 3.85, in fast range
    float f = __sinf(mag) / mag;
    #pragma unroll
    for (int i = 0; i < 6; ++i) b[i] = f * a[i];
}
__device__ __forceinline__ void apply_rotor(float s, const float b[6], const float v[4], float o[4]) {
    float t12 = b[0], t13 = b[1], t14 = b[2], t23 = b[3], t24 = b[4], t34 = b[5];
    float v1 = v[0], v2 = v[1], v3 = v[2], v4 = v[3];
    float s2 = s * s;
    float ts = 2.0f * s;
    o[0] = v1 * (s2 - t12*t12 - t13*t13 - t14*t14) + ts * ( v2*t12 + v3*t13 + v4*t14);
    o[1] = v2 * (s2 - t12*t12 - t23*t23 - t24*t24) + ts * (-v1*t12 + v3*t23 + v4*t24);
    o[2] = v3 * (s2 - t13*t13 - t23*t23 - t34*t34) + ts * (-v1*t13 - v2*t23 + v4*t34);
    o[3] = v4 * (s2 - t14*t14 - t24*t24 - t34*t34) + ts * (-v1*t14 - v2*t24 - v3*t34);
}

// ---------------- weight pack: W[K][N] fp32 -> Bpack[nfrag][ktile][lane*8] bf16 -------
// frag (nf, kt): lane l element j = W[kt*32 + (l>>4)*8 + j][nf*16 + (l&15)]
__global__ __launch_bounds__(256)
void pack_b4(const float* __restrict__ w0, const float* __restrict__ w1,
             const float* __restrict__ w2, const float* __restrict__ w3,
             us* __restrict__ o0, us* __restrict__ o1,
             us* __restrict__ o2, us* __restrict__ o3, int Kd, int N)
{
    const float* W = (blockIdx.z == 0) ? w0 : (blockIdx.z == 1) ? w1 : (blockIdx.z == 2) ? w2 : w3;
    us* O = (blockIdx.z == 0) ? o0 : (blockIdx.z == 1) ? o1 : (blockIdx.z == 2) ? o2 : o3;
    if (W == nullptr) return;
    int nf = blockIdx.x;                         // N/16 frag-rows
    int kt = blockIdx.y * 4 + (threadIdx.x >> 6);
    int l = threadIdx.x & 63;
    int n = nf * 16 + (l & 15);
    int k0 = kt * 32 + (l >> 4) * 8;
    union { us u[8]; uint4 v; } pk;
    #pragma unroll
    for (int j = 0; j < 8; ++j)
        pk.u[j] = f2bf(W[(size_t)(k0 + j) * N + n]);
    *(uint4*)(O + ((size_t)nf * (Kd >> 5) + kt) * 512 + l * 8) = pk.v;
}

// ---------------- fp32 -> bf16 convert ----------------
__global__ __launch_bounds__(256)
void cvt_bf16_kernel(const float* __restrict__ in, us* __restrict__ out)
{
    size_t i = ((size_t)blockIdx.x * 256 + threadIdx.x) * 8;
    float4 v0 = *(const float4*)(in + i);
    float4 v1 = *(const float4*)(in + i + 4);
    union { us u[8]; uint4 v; } pk;
    pk.u[0] = f2bf(v0.x); pk.u[1] = f2bf(v0.y); pk.u[2] = f2bf(v0.z); pk.u[3] = f2bf(v0.w);
    pk.u[4] = f2bf(v1.x); pk.u[5] = f2bf(v1.y); pk.u[6] = f2bf(v1.z); pk.u[7] = f2bf(v1.w);
    *(uint4*)(out + i) = pk.v;
}

// ---------------- XCD-chunked block swizzle (bijective, nwg % 8 == 0) ----------------
__device__ __forceinline__ int xcd_swz(int bid, int nwg) {
    int cpx = nwg >> 3;
    return (bid & 7) * cpx + (bid >> 3);
}

// ============ 128x128 GEMM core: A via LDS ring-3 (dist 2), B in regs (dist 2) ============
// 4 waves, wave tile 64x64, frags 4x4, 16 MFMA / K-tile / wave, BK=32.
// LDS 24KB = 3 x 8KB A-buffers. A-swizzle (both sides, measured 0-conflict r3):
// 16B unit u of row r holds logical unit u ^ ((r>>1)&3).
// Per iteration: ds_read A(t) frags FIRST (latency covered by staging issues),
// stage A(t+2) via gload_lds, MFMA with parity b-set, THEN reload that b-set with
// B(t+2) (anti-dep keeps it after the MFMA; full-iteration latency cover, no copies).
// vmcnt(6) at iter end: 6 = this iter's {2 gload + 4 B} -> A(t+1) guaranteed landed.

#define GBAR()  do { __builtin_amdgcn_s_barrier(); __builtin_amdgcn_sched_barrier(0); } while (0)

__device__ __forceinline__ void gemm128_core(
    const us* __restrict__ Ab, const us* __restrict__ Bp, int Kd, int bn,
    short* lds, f32x4 (&acc)[4][4])
{
    const int tid = threadIdx.x;
    const int l = tid & 63, w = tid >> 6;
    const int wr = w >> 1, wc = w & 1;
    const int fr = l & 15, fq = l >> 4;
    const int nkt = Kd >> 5;                         // 32, even

    #pragma unroll
    for (int i = 0; i < 4; ++i)
        #pragma unroll
        for (int j = 0; j < 4; ++j)
            acc[i][j] = (f32x4){0.f, 0.f, 0.f, 0.f};

    // B fragment pointers: nfrag = bn/16 + wc*4 + ni ; per-tile stride 512 shorts
    const us* bptr[4];
    #pragma unroll
    for (int ni = 0; ni < 4; ++ni)
        bptr[ni] = Bp + ((size_t)((bn >> 4) + wc * 4 + ni) * nkt) * 512 + l * 8;

    // A staging: thread covers row sr (0-63) unit su in h0 and row sr+64 in h1
    const int sr = tid >> 2, su = tid & 3;
    const int slu = su ^ ((sr >> 1) & 3);            // pre-swizzled global unit
    const us* gA0 = Ab + (size_t)sr * Kd + slu * 8;
    const us* gA1 = gA0 + (size_t)64 * Kd;

    const int swu = (fq ^ ((fr >> 1) & 3)) * 8;      // read-side swizzled unit
    const int arow = (wr * 64 + fr) * 32 + swu;      // + mi*512

    // prologue: A tiles 0,1,2 -> bufs 0,1,2 ; wait A(0); B tiles 0,1 -> regs
    gload_lds16(gA0,      lds + tid * 8);
    gload_lds16(gA1,      lds + 2048 + tid * 8);
    gload_lds16(gA0 + 32, lds + 4096 + tid * 8);
    gload_lds16(gA1 + 32, lds + 6144 + tid * 8);
    gload_lds16(gA0 + 64, lds + 8192 + tid * 8);
    gload_lds16(gA1 + 64, lds + 10240 + tid * 8);
    asm volatile("s_waitcnt vmcnt(4)" ::: "memory");   // A(0) landed
    short8 bA[4], bB[4];
    #pragma unroll
    for (int ni = 0; ni < 4; ++ni) bA[ni] = *(const short8*)(bptr[ni]);
    #pragma unroll
    for (int ni = 0; ni < 4; ++ni) bB[ni] = *(const short8*)(bptr[ni] + 512);
    GBAR();

    for (int t = 0; t < nkt; t += 2) {
        // ---- even sub-iter (uses bA) ----
        {
            const int cb = (t % 3) * 4096;
            const int sb = ((t + 2) % 3) * 4096;
            const int tp = (t + 2 < nkt) ? (t + 2) : (nkt - 1);
            short8 a[4];
            #pragma unroll
            for (int mi = 0; mi < 4; ++mi)
                a[mi] = *(const short8*)(lds + cb + arow + mi * 512);
            gload_lds16(gA0 + tp * 32, lds + sb + tid * 8);
            gload_lds16(gA1 + tp * 32, lds + sb + 2048 + tid * 8);
            __builtin_amdgcn_s_setprio(1);
            #pragma unroll
            for (int mi = 0; mi < 4; ++mi)
                #pragma unroll
                for (int ni = 0; ni < 4; ++ni)
                    acc[mi][ni] = __builtin_amdgcn_mfma_f32_16x16x32_bf16(bA[ni], a[mi], acc[mi][ni], 0, 0, 0);
            __builtin_amdgcn_sched_barrier(0);
            __builtin_amdgcn_s_setprio(0);
            #pragma unroll
            for (int ni = 0; ni < 4; ++ni)          // reload bA with B(t+2)
                bA[ni] = *(const short8*)(bptr[ni] + (size_t)tp * 512);
            asm volatile("s_waitcnt vmcnt(6)" ::: "memory");   // A(t+1) landed
            GBAR();
        }
        // ---- odd sub-iter (uses bB) ----
        {
            const int t1 = t + 1;
            const int cb = (t1 % 3) * 4096;
            const int sb = ((t1 + 2) % 3) * 4096;
            const int tp = (t1 + 2 < nkt) ? (t1 + 2) : (nkt - 1);
            short8 a[4];
            #pragma unroll
            for (int mi = 0; mi < 4; ++mi)
                a[mi] = *(const short8*)(lds + cb + arow + mi * 512);
            gload_lds16(gA0 + tp * 32, lds + sb + tid * 8);
            gload_lds16(gA1 + tp * 32, lds + sb + 2048 + tid * 8);
            __builtin_amdgcn_s_setprio(1);
            #pragma unroll
            for (int mi = 0; mi < 4; ++mi)
                #pragma unroll
                for (int ni = 0; ni < 4; ++ni)
                    acc[mi][ni] = __builtin_amdgcn_mfma_f32_16x16x32_bf16(bB[ni], a[mi], acc[mi][ni], 0, 0, 0);
            __builtin_amdgcn_sched_barrier(0);
            __builtin_amdgcn_s_setprio(0);
            #pragma unroll
            for (int ni = 0; ni < 4; ++ni)          // reload bB with B(t1+2)
                bB[ni] = *(const short8*)(bptr[ni] + (size_t)tp * 512);
            asm volatile("s_waitcnt vmcnt(6)" ::: "memory");   // A(t1+1) landed
            GBAR();
        }
    }
    // output mapping: row = bm + wr*64 + mi*16 + fr; col = bn + wc*64 + ni*16 + fq*4 + v
}

// ---------------- GEMM A: x @ [wk1|wq1|wv], fused epilogues, bf16 out ----------------
__global__ __launch_bounds__(256, 3)
void gemm_fused3(const us* __restrict__ xb,
                 const us* __restrict__ w0p, const us* __restrict__ w1p, const us* __restrict__ w2p,
                 const float* __restrict__ b0, const float* __restrict__ b1, const float* __restrict__ b2,
                 us* __restrict__ o0, us* __restrict__ o1, us* __restrict__ o2)
{
    __shared__ short lds[12288];
    const int wg = xcd_swz(blockIdx.x, 1536);
    const int bm = (wg / 24) * 128;              // bm-major: 24 col-blocks share A-panel
    const int col = wg % 24;
    const int r = col >> 3;                      // 0=k,1=q,2=v
    const int bn = (col & 7) * 128;
    const us* Bp = (r == 0) ? w0p : (r == 1) ? w1p : w2p;
    const float* bias = (r == 0) ? b0 : (r == 1) ? b1 : b2;
    us* outp = (r == 0) ? o0 : (r == 1) ? o1 : o2;
    f32x4 acc[4][4];
    gemm128_core(xb + (size_t)bm * D_DIM, Bp, D_DIM, bn, lds, acc);
    const int l = threadIdx.x & 63, w = threadIdx.x >> 6;
    const int wr = w >> 1, wc = w & 1, fr = l & 15, fq = l >> 4;
    #pragma unroll
    for (int mi = 0; mi < 4; ++mi) {
        int row = bm + wr * 64 + mi * 16 + fr;
        #pragma unroll
        for (int ni = 0; ni < 4; ++ni) {
            int c0 = bn + wc * 64 + ni * 16 + fq * 4;
            float4 bs = *(const float4*)(bias + c0);
            float v0 = acc[mi][ni][0] + bs.x, v1 = acc[mi][ni][1] + bs.y;
            float v2 = acc[mi][ni][2] + bs.z, v3 = acc[mi][ni][3] + bs.w;
            if (r < 2) { v0 = gelu_fast(v0); v1 = gelu_fast(v1); v2 = gelu_fast(v2); v3 = gelu_fast(v3); }
            ushort4 pk; pk.x = f2bf(v0); pk.y = f2bf(v1); pk.z = f2bf(v2); pk.w = f2bf(v3);
            *(ushort4*)(outp + (size_t)row * D_DIM + c0) = pk;
        }
    }
}

// ---------------- GEMM B: angles = tanh(H @ w2 + b2)*pi/2, bf16 out ----------------
__global__ __launch_bounds__(256, 3)
void gemm_angles(const us* __restrict__ Hk, const us* __restrict__ Hq,
                 const us* __restrict__ wk2p, const us* __restrict__ wq2p,
                 const float* __restrict__ bk2, const float* __restrict__ bq2,
                 us* __restrict__ ak, us* __restrict__ aq)
{
    __shared__ short lds[12288];
    const int wg = xcd_swz(blockIdx.x, 1536);
    const int z = wg / 768;
    const int rem = wg % 768;
    const int bm = (rem / 12) * 128;             // bm-major within z
    const int bn = (rem % 12) * 128;
    const us* A  = z ? Hq : Hk;
    const us* Bp = z ? wq2p : wk2p;
    const float* bias = z ? bq2 : bk2;
    us* outp = z ? aq : ak;
    f32x4 acc[4][4];
    gemm128_core(A + (size_t)bm * D_DIM, Bp, D_DIM, bn, lds, acc);
    const int l = threadIdx.x & 63, w = threadIdx.x >> 6;
    const int wr = w >> 1, wc = w & 1, fr = l & 15, fq = l >> 4;
    #pragma unroll
    for (int mi = 0; mi < 4; ++mi) {
        int row = bm + wr * 64 + mi * 16 + fr;
        #pragma unroll
        for (int ni = 0; ni < 4; ++ni) {
            int c0 = bn + wc * 64 + ni * 16 + fq * 4;
            float4 bs = *(const float4*)(bias + c0);
            ushort4 pk;
            pk.x = f2bf(tanh_fast(acc[mi][ni][0] + bs.x) * HALF_PI);
            pk.y = f2bf(tanh_fast(acc[mi][ni][1] + bs.y) * HALF_PI);
            pk.z = f2bf(tanh_fast(acc[mi][ni][2] + bs.z) * HALF_PI);
            pk.w = f2bf(tanh_fast(acc[mi][ni][3] + bs.w) * HALF_PI);
            *(ushort4*)(outp + (size_t)row * N6 + c0) = pk;
        }
    }
}

// ---------------- GEMM C: out = x + rn @ wo + bo, fp32 out ----------------
__global__ __launch_bounds__(256, 3)
void gemm_final(const us* __restrict__ rn, const us* __restrict__ wop,
                const float* __restrict__ bo, const float* __restrict__ x,
                float* __restrict__ out)
{
    __shared__ short lds[12288];
    const int wg = xcd_swz(blockIdx.x, 512);
    const int bm = (wg / 8) * 128;
    const int bn = (wg % 8) * 128;
    f32x4 acc[4][4];
    gemm128_core(rn + (size_t)bm * D_DIM, wop, D_DIM, bn, lds, acc);
    const int l = threadIdx.x & 63, w = threadIdx.x >> 6;
    const int wr = w >> 1, wc = w & 1, fr = l & 15, fq = l >> 4;
    #pragma unroll
    for (int mi = 0; mi < 4; ++mi) {
        int row = bm + wr * 64 + mi * 16 + fr;
        #pragma unroll
        for (int ni = 0; ni < 4; ++ni) {
            int c0 = bn + wc * 64 + ni * 16 + fq * 4;
            size_t off = (size_t)row * D_DIM + c0;
            float4 bs = *(const float4*)(bo + c0);
            float4 rx = *(const float4*)(x + off);
            float4 o;
            o.x = acc[mi][ni][0] + bs.x + rx.x;
            o.y = acc[mi][ni][1] + bs.y + rx.y;
            o.z = acc[mi][ni][2] + bs.z + rx.z;
            o.w = acc[mi][ni][3] + bs.w + rx.w;
            *(float4*)(out + off) = o;
        }
    }
}

// ------- scan phase 1: rotate(value by key rotor) IN PLACE + per-chunk sums -------
// Writes the bf16-rounded rotated value back to `value`; accumulates the SAME
// rounded values so phase 3's running sum is consistent.
__global__ __launch_bounds__(256)
void rot_chunk_sum(us* __restrict__ value, const us* __restrict__ ak,
                   float4* __restrict__ sums)
{
    int bc = blockIdx.x;
    int b = bc >> 8, c = bc & 255;
    int k = threadIdx.x;
    float4 acc = make_float4(0.f, 0.f, 0.f, 0.f);
    size_t row0 = (size_t)b * L_DIM + c * CHUNK_LEN;
    for (int i = 0; i < CHUNK_LEN; ++i) {
        size_t row = row0 + i;
        ushort4 uv = *(const ushort4*)(value + row * D_DIM + k * 4);
        const unsigned int* ap = (const unsigned int*)(ak + row * N6 + k * 6);
        unsigned int a0 = ap[0], a1 = ap[1], a2 = ap[2];
        float a[6] = { bf2f(a0 & 0xffff), bf2f(a0 >> 16), bf2f(a1 & 0xffff),
                       bf2f(a1 >> 16), bf2f(a2 & 0xffff), bf2f(a2 >> 16) };
        float s, bb[6];
        rotor_from_angles(a, s, bb);
        float v[4] = {bf2f(uv.x), bf2f(uv.y), bf2f(uv.z), bf2f(uv.w)}, o[4];
        apply_rotor(s, bb, v, o);
        ushort4 pkr;
        pkr.x = f2bf(o[0]); pkr.y = f2bf(o[1]); pkr.z = f2bf(o[2]); pkr.w = f2bf(o[3]);
        *(ushort4*)(value + row * D_DIM + k * 4) = pkr;
        acc.x += bf2f(pkr.x); acc.y += bf2f(pkr.y); acc.z += bf2f(pkr.z); acc.w += bf2f(pkr.w);
    }
    sums[(size_t)bc * 256 + k] = acc;
}

// ---------------- scan phase 2: exclusive scan of chunk sums ----------------
__global__ __launch_bounds__(256)
void scan_chunks_kernel(const float4* __restrict__ sums, float4* __restrict__ carry)
{
    int b = blockIdx.x >> 8;
    int k = blockIdx.x & 255;
    int c = threadIdx.x;
    __shared__ float4 sh[CHUNKS];
    float4 v = sums[((size_t)(b * CHUNKS + c)) * 256 + k];
    sh[c] = v;
    __syncthreads();
    for (int off = 1; off < CHUNKS; off <<= 1) {
        float4 t = make_float4(0.f, 0.f, 0.f, 0.f);
        if (c >= off) t = sh[c - off];
        __syncthreads();
        v.x += t.x; v.y += t.y; v.z += t.z; v.w += t.w;
        sh[c] = v;
        __syncthreads();
    }
    float4 ex = make_float4(0.f, 0.f, 0.f, 0.f);
    if (c > 0) ex = sh[c - 1];
    carry[((size_t)(b * CHUNKS + c)) * 256 + k] = ex;
}

// ------- scan phase 3: cumsum of (pre-rotated) value + reversed query rotor + LN -------
__global__ __launch_bounds__(256)
void scan_apply_ln(const us* __restrict__ value, const us* __restrict__ aq,
                   const float4* __restrict__ carry,
                   const float* __restrict__ g, const float* __restrict__ bta,
                   us* __restrict__ rn)
{
    int bc = blockIdx.x;
    int b = bc >> 8, c = bc & 255;
    int k = threadIdx.x;
    int wv = k >> 6, lane = k & 63;
    float4 run = carry[(size_t)bc * 256 + k];
    float4 gv = *(const float4*)(g + k * 4);
    float4 bv = *(const float4*)(bta + k * 4);
    __shared__ float reds[4], redq[4];
    for (int i = 0; i < CHUNK_LEN; ++i) {
        int l = c * CHUNK_LEN + i;
        size_t row = (size_t)b * L_DIM + l;
        ushort4 uv = *(const ushort4*)(value + row * D_DIM + k * 4);
        run.x += bf2f(uv.x); run.y += bf2f(uv.y); run.z += bf2f(uv.z); run.w += bf2f(uv.w);
        const unsigned int* aqp = (const unsigned int*)(aq + row * N6 + k * 6);
        unsigned int qa0 = aqp[0], qa1 = aqp[1], qa2 = aqp[2];
        float aq6[6] = { bf2f(qa0 & 0xffff), bf2f(qa0 >> 16), bf2f(qa1 & 0xffff),
                         bf2f(qa1 >> 16), bf2f(qa2 & 0xffff), bf2f(qa2 >> 16) };
        float qs, qb[6];
        rotor_from_angles(aq6, qs, qb);
        #pragma unroll
        for (int t = 0; t < 6; ++t) qb[t] = -qb[t];
        float mem[4] = {run.x, run.y, run.z, run.w}, o2[4];
        apply_rotor(qs, qb, mem, o2);
        float inv = rsqrtf((float)(l + 1));
        o2[0] *= inv; o2[1] *= inv; o2[2] *= inv; o2[3] *= inv;
        float sm = o2[0] + o2[1] + o2[2] + o2[3];
        float qm = o2[0]*o2[0] + o2[1]*o2[1] + o2[2]*o2[2] + o2[3]*o2[3];
        #pragma unroll
        for (int off = 1; off < 64; off <<= 1) {
            sm += __shfl_xor(sm, off);
            qm += __shfl_xor(qm, off);
        }
        if (lane == 0) { reds[wv] = sm; redq[wv] = qm; }
        __syncthreads();
        sm = reds[0] + reds[1] + reds[2] + reds[3];
        qm = redq[0] + redq[1] + redq[2] + redq[3];
        float mu = sm * (1.0f / 1024.0f);
        float var = qm * (1.0f / 1024.0f) - mu * mu;
        float rstd = rsqrtf(var + 1e-5f);
        ushort4 pk;
        pk.x = f2bf((o2[0] - mu) * rstd * gv.x + bv.x);
        pk.y = f2bf((o2[1] - mu) * rstd * gv.y + bv.y);
        pk.z = f2bf((o2[2] - mu) * rstd * gv.z + bv.z);
        pk.w = f2bf((o2[3] - mu) * rstd * gv.w + bv.w);
        *(ushort4*)(rn + row * D_DIM + k * 4) = pk;
        __syncthreads();
    }
}

extern "C" void kernel_launch(void* const* d_in, const int* in_sizes, int n_in,
                              void* d_out, int out_size, void* d_ws, size_t ws_size,
                              hipStream_t stream)
{
    const float* x   = (const float*)d_in[0];
    const float* wk1 = (const float*)d_in[1];
    const float* bk1 = (const float*)d_in[2];
    const float* wk2 = (const float*)d_in[3];
    const float* bk2 = (const float*)d_in[4];
    const float* wq1 = (const float*)d_in[5];
    const float* bq1 = (const float*)d_in[6];
    const float* wq2 = (const float*)d_in[7];
    const float* bq2 = (const float*)d_in[8];
    const float* wv  = (const float*)d_in[9];
    const float* bv  = (const float*)d_in[10];
    const float* lng = (const float*)d_in[11];
    const float* lnb = (const float*)d_in[12];
    const float* wo  = (const float*)d_in[13];
    const float* bo  = (const float*)d_in[14];
    float* out = (float*)d_out;

    char* ws = (char*)d_ws;
    us* xb    = (us*)(ws);                       // 16 MB (later aliased as rn)
    us* Hk    = (us*)(ws + (16ull  << 20));      // 16 MB
    us* Hq    = (us*)(ws + (32ull  << 20));      // 16 MB
    us* val   = (us*)(ws + (48ull  << 20));      // 16 MB
    us* ak    = (us*)(ws + (64ull  << 20));      // 24 MB
    us* aq    = (us*)(ws + (88ull  << 20));      // 24 MB
    float4* sums  = (float4*)(ws + (112ull << 20)); // 2 MB
    float4* carry = (float4*)(ws + (114ull << 20)); // 2 MB
    us* wk1p  = (us*)(ws + (116ull << 20));      // 2 MB
    us* wq1p  = (us*)(ws + (118ull << 20));      // 2 MB
    us* wvp   = (us*)(ws + (120ull << 20));      // 2 MB
    us* wop   = (us*)(ws + (122ull << 20));      // 2 MB
    us* wk2p  = (us*)(ws + (124ull << 20));      // 3 MB
    us* wq2p  = (us*)(ws + (127ull << 20));      // 3 MB -> 130 MB total
    us* rn    = xb;                              // alias: xb dead after gemm_fused3

    dim3 blk(256);
    // weight packs: 4x DxD, 2x DxN6  (grid: N/16 frags x K/128 x z)
    pack_b4<<<dim3(D_DIM / 16, D_DIM / 128, 4), blk, 0, stream>>>(
        wk1, wq1, wv, wo, wk1p, wq1p, wvp, wop, D_DIM, D_DIM);
    pack_b4<<<dim3(N6 / 16, D_DIM / 128, 2), blk, 0, stream>>>(
        wk2, wq2, nullptr, nullptr, wk2p, wq2p, nullptr, nullptr, D_DIM, N6);
    cvt_bf16_kernel<<<dim3(M_ROWS * D_DIM / (256 * 8)), blk, 0, stream>>>(x, xb);

    // GEMM A: x @ [wk1|wq1|wv] -> Hk, Hq, val (bf16); 1536 blocks, bm-major + XCD chunk
    gemm_fused3<<<dim3(1536), blk, 0, stream>>>(
        xb, wk1p, wq1p, wvp, bk1, bq1, bv, Hk, Hq, val);
    // GEMM B: angles (k then q); 1536 blocks
    gemm_angles<<<dim3(1536), blk, 0, stream>>>(
        Hk, Hq, wk2p, wq2p, bk2, bq2, ak, aq);
    // scan chain (phase 1 rotates val in place)
    rot_chunk_sum<<<dim3(B_DIM * CHUNKS), blk, 0, stream>>>(val, ak, sums);
    scan_chunks_kernel<<<dim3(B_DIM * K_DIM), blk, 0, stream>>>(sums, carry);
    scan_apply_ln<<<dim3(B_DIM * CHUNKS), blk, 0, stream>>>(val, aq, carry, lng, lnb, rn);
    // GEMM C: out = x + rn @ wo + bo; 512 blocks
    gemm_final<<<dim3(512), blk, 0, stream>>>(rn, wop, bo, x, out);
}